// Round 16
// baseline (33.733 us; speedup 1.0000x reference)
//
#include <hip/hip_runtime.h>

#define NN 50000
#define NE 100000
#define NREL 64
#define D 64
#define RCAP 1280      // per-relation bucket capacity (expected ~676)
#define SCAP 8192      // self-only bucket capacity (expected ~6766)
#define CSTR 16        // cursor stride in ints (64 B per counter)
#define BR   8         // blocks per relation
#define SBLK 64        // self-only blocks
#define FILL_BLOCKS 128
#define FILL_ITERS  2

typedef unsigned long long u64;
using f16x8 = __attribute__((ext_vector_type(8))) _Float16;
using f32x4 = __attribute__((ext_vector_type(4))) float;

// ws layout (bytes):
// packed @0 (400KB) | cursor @400K (4.2KB) | rbucket @408K (327.7KB) |
// sbucket @736K (32KB) | h2 @768K (6.4MB) | wsT @7168K (8KB) | w16T @7176K (512KB)
#define WS_CURSOR  (400 * 1024)
#define WS_RBUCKET (408 * 1024)
#define WS_SBUCKET (736 * 1024)
#define WS_H2      (768 * 1024)
#define WS_WST     (7168 * 1024)
#define WS_W16T    (7176 * 1024)

struct H4 { _Float16 v[4]; };   // 8-byte pack

// init packed/cursor + convert h -> f16, weight/wself -> f16 TRANSPOSED [n][k]
__global__ __launch_bounds__(256) void k_pre(
    const float* __restrict__ h, const float* __restrict__ weight,
    const float* __restrict__ wself, u64* __restrict__ packed,
    int* __restrict__ cursor, _Float16* __restrict__ h2,
    _Float16* __restrict__ w16T, _Float16* __restrict__ wsT)
{
    const int t = blockIdx.x * 256 + threadIdx.x;
    const int nthr = gridDim.x * 256;
    for (int i = t; i < NN; i += nthr) packed[i] = 0ull;
    if (t < 65) cursor[t * CSTR] = 0;

    // h: coalesced f32x4 -> f16x4
    const float4* __restrict__ hf4 = reinterpret_cast<const float4*>(h);
    H4* __restrict__ o4 = reinterpret_cast<H4*>(h2);
    for (int m = t; m < NN * (D / 4); m += nthr) {
        const float4 p = hf4[m];
        H4 o;
        o.v[0] = (_Float16)p.x; o.v[1] = (_Float16)p.y;
        o.v[2] = (_Float16)p.z; o.v[3] = (_Float16)p.w;
        o4[m] = o;
    }

    // weight: read row-major float4, write transposed f16  w16T[r][n][k] = W[r][k][n]
    const float4* __restrict__ W4 = reinterpret_cast<const float4*>(weight);
    for (int m = t; m < NREL * D * D / 4; m += nthr) {
        const float4 w = W4[m];
        const int r   = m >> 10;           // 1024 float4 per relation
        const int rem = m & 1023;
        const int k   = rem >> 4;
        const int n0  = (rem & 15) << 2;
        _Float16* __restrict__ base = w16T + ((size_t)r << 12) + k;
        base[(size_t)(n0 + 0) * D] = (_Float16)w.x;
        base[(size_t)(n0 + 1) * D] = (_Float16)w.y;
        base[(size_t)(n0 + 2) * D] = (_Float16)w.z;
        base[(size_t)(n0 + 3) * D] = (_Float16)w.w;
    }

    // wself -> wsT[n][k]
    const float4* __restrict__ WS4 = reinterpret_cast<const float4*>(wself);
    for (int m = t; m < D * D / 4; m += nthr) {
        const float4 w = WS4[m];
        const int k  = m >> 4;
        const int n0 = (m & 15) << 2;
        wsT[(size_t)(n0 + 0) * D + k] = (_Float16)w.x;
        wsT[(size_t)(n0 + 1) * D + k] = (_Float16)w.y;
        wsT[(size_t)(n0 + 2) * D + k] = (_Float16)w.z;
        wsT[(size_t)(n0 + 3) * D + k] = (_Float16)w.w;
    }
}

// one 64-bit atomicMax per edge: key = (e+1)<<22 | rel<<16 | src
__global__ void k_scatter(const int* __restrict__ edges, u64* __restrict__ packed) {
    int e = blockIdx.x * blockDim.x + threadIdx.x;
    if (e < NE) {
        int s = edges[e * 3 + 0];
        int r = edges[e * 3 + 1];
        int d = edges[e * 3 + 2];
        u64 key = ((u64)(e + 1) << 22) | ((u64)r << 16) | (u64)s;
        atomicMax(&packed[d], key);
    }
}

// block-aggregated bucket fill: LDS histogram -> 1 global atomic per (block, rel)
__global__ __launch_bounds__(256) void k_fill(
    const u64* __restrict__ packed, int* __restrict__ cursor,
    unsigned* __restrict__ rbucket, unsigned* __restrict__ sbucket)
{
    __shared__ int hcnt[65];
    __shared__ int hbase[65];
    const int t = threadIdx.x;
    if (t < 65) hcnt[t] = 0;
    __syncthreads();

    int      myr[FILL_ITERS];
    int      myslot[FILL_ITERS];
    unsigned myent[FILL_ITERS];

    #pragma unroll
    for (int it = 0; it < FILL_ITERS; ++it) {
        const int v = (blockIdx.x * FILL_ITERS + it) * 256 + t;
        myr[it] = -1;
        if (v < NN) {
            u64 key = packed[v];
            if (key) {
                myr[it]   = (int)((key >> 16) & 63);
                myent[it] = ((unsigned)v << 16) | (unsigned)(key & 0xFFFF);
            } else {
                myr[it]   = 64;
                myent[it] = (unsigned)v;
            }
            myslot[it] = atomicAdd(&hcnt[myr[it]], 1);
        }
    }
    __syncthreads();
    if (t < 65 && hcnt[t] > 0)
        hbase[t] = atomicAdd(&cursor[t * CSTR], hcnt[t]);
    __syncthreads();

    #pragma unroll
    for (int it = 0; it < FILL_ITERS; ++it) {
        const int r = myr[it];
        if (r >= 0) {
            const int p = hbase[r] + myslot[it];
            if (r < 64) { if (p < RCAP) rbucket[r * RCAP + p] = myent[it]; }
            else        { if (p < SCAP) sbucket[p] = myent[it]; }
        }
    }
}

// MFMA compute, zero LDS / zero staging: B-frags are direct 16B global loads
// from the pre-transposed f16 weights (L2-resident).
// A-frag (16x16x32_f16): lane l -> row m=l&15, k=(l>>4)*8+j
// B-frag: lane l -> col n=l&15, k=(l>>4)*8+j  -> w16T[r][n][kbase..+8] contiguous
// C/D   : lane l, reg q -> row m=(l>>4)*4+q, col n=l&15
__global__ __launch_bounds__(256) void k_compute(
    const _Float16* __restrict__ h2, const _Float16* __restrict__ w16T,
    const _Float16* __restrict__ wsT, const unsigned* __restrict__ rbucket,
    const unsigned* __restrict__ sbucket, const int* __restrict__ cursor,
    float* __restrict__ out)
{
    const int lane = threadIdx.x & 63;
    const int wv   = threadIdx.x >> 6;
    const bool isRel = blockIdx.x < NREL * BR;

    int r = 64, wslot, wstride, cnt;
    const unsigned* __restrict__ seg;
    if (isRel) {
        r = blockIdx.x / BR;
        wslot = (blockIdx.x % BR) * 4 + wv;
        wstride = BR * 4;
        seg = rbucket + r * RCAP;
        cnt = min(cursor[r * CSTR], RCAP);
    } else {
        wslot = (blockIdx.x - NREL * BR) * 4 + wv;
        wstride = SBLK * 4;
        seg = sbucket;
        cnt = min(cursor[64 * CSTR], SCAP);
    }
    if (cnt == 0 || wslot * 16 >= cnt) return;

    const int kbase = (lane >> 4) * 8;
    const int ncol  = lane & 15;

    // ---- B-frags: direct 16B loads, no LDS ----
    f16x8 bws[4][2];
    #pragma unroll
    for (int nt = 0; nt < 4; ++nt)
        #pragma unroll
        for (int ks = 0; ks < 2; ++ks)
            bws[nt][ks] = *reinterpret_cast<const f16x8*>(
                wsT + (size_t)(nt * 16 + ncol) * D + ks * 32 + kbase);

    f16x8 bw[4][2];
    if (isRel) {
        const _Float16* __restrict__ wr = w16T + ((size_t)r << 12);
        #pragma unroll
        for (int nt = 0; nt < 4; ++nt)
            #pragma unroll
            for (int ks = 0; ks < 2; ++ks)
                bw[nt][ks] = *reinterpret_cast<const f16x8*>(
                    wr + (size_t)(nt * 16 + ncol) * D + ks * 32 + kbase);
    }

    // ---- tile loop ----
    for (int t = wslot; t * 16 < cnt; t += wstride) {
        const int myidx = min(t * 16 + ncol, cnt - 1);   // this lane's tile row = ncol
        const unsigned ent = seg[myidx];
        const int v = isRel ? (int)(ent >> 16) : (int)ent;
        const int s = (int)(ent & 0xFFFF);

        f32x4 c[4];
        #pragma unroll
        for (int nt = 0; nt < 4; ++nt) c[nt] = (f32x4){0.f, 0.f, 0.f, 0.f};

        // self part: A = h2[v]
        {
            const f16x8 a0 = *reinterpret_cast<const f16x8*>(h2 + (size_t)v * D + kbase);
            const f16x8 a1 = *reinterpret_cast<const f16x8*>(h2 + (size_t)v * D + 32 + kbase);
            #pragma unroll
            for (int nt = 0; nt < 4; ++nt) {
                c[nt] = __builtin_amdgcn_mfma_f32_16x16x32_f16(a0, bws[nt][0], c[nt], 0, 0, 0);
                c[nt] = __builtin_amdgcn_mfma_f32_16x16x32_f16(a1, bws[nt][1], c[nt], 0, 0, 0);
            }
        }
        // rel part: A = h2[s]
        if (isRel) {
            const f16x8 a0 = *reinterpret_cast<const f16x8*>(h2 + (size_t)s * D + kbase);
            const f16x8 a1 = *reinterpret_cast<const f16x8*>(h2 + (size_t)s * D + 32 + kbase);
            #pragma unroll
            for (int nt = 0; nt < 4; ++nt) {
                c[nt] = __builtin_amdgcn_mfma_f32_16x16x32_f16(a0, bw[nt][0], c[nt], 0, 0, 0);
                c[nt] = __builtin_amdgcn_mfma_f32_16x16x32_f16(a1, bw[nt][1], c[nt], 0, 0, 0);
            }
        }

        // store: reg q holds row m=(lane>>4)*4+q, col = ncol
        int vrow[4];
        #pragma unroll
        for (int q = 0; q < 4; ++q)
            vrow[q] = __shfl(v, (lane >> 4) * 4 + q, 64);

        #pragma unroll
        for (int nt = 0; nt < 4; ++nt)
            #pragma unroll
            for (int q = 0; q < 4; ++q)
                out[(size_t)vrow[q] * D + nt * 16 + ncol] = c[nt][q];
    }
}

extern "C" void kernel_launch(void* const* d_in, const int* in_sizes, int n_in,
                              void* d_out, int out_size, void* d_ws, size_t ws_size,
                              hipStream_t stream) {
    const float* h      = (const float*)d_in[0];
    const int*   edges  = (const int*)d_in[1];
    const float* weight = (const float*)d_in[2];
    const float* wself  = (const float*)d_in[3];
    float* out = (float*)d_out;

    char* ws = (char*)d_ws;
    u64*      packed  = (u64*)ws;
    int*      cursor  = (int*)(ws + WS_CURSOR);
    unsigned* rbucket = (unsigned*)(ws + WS_RBUCKET);
    unsigned* sbucket = (unsigned*)(ws + WS_SBUCKET);
    _Float16* h2      = (_Float16*)(ws + WS_H2);
    _Float16* wsT     = (_Float16*)(ws + WS_WST);
    _Float16* w16T    = (_Float16*)(ws + WS_W16T);

    k_pre<<<512, 256, 0, stream>>>(h, weight, wself, packed, cursor, h2, w16T, wsT);
    k_scatter<<<(NE + 255) / 256, 256, 0, stream>>>(edges, packed);
    k_fill<<<FILL_BLOCKS, 256, 0, stream>>>(packed, cursor, rbucket, sbucket);
    k_compute<<<NREL * BR + SBLK, 256, 0, stream>>>(h2, w16T, wsT, rbucket, sbucket, cursor, out);
}